// Round 1
// baseline (397.979 us; speedup 1.0000x reference)
//
#include <hip/hip_runtime.h>
#include <hip/hip_bf16.h>
#include <math.h>

// ---------- types / helpers ----------
typedef __attribute__((ext_vector_type(8))) short bf16x8;
typedef __attribute__((ext_vector_type(4))) float f32x4;
typedef __attribute__((ext_vector_type(4))) unsigned short u16x4;

static __device__ __forceinline__ float bf2f(unsigned short u) {
    union { unsigned int i; float f; } v; v.i = ((unsigned int)u) << 16; return v.f;
}
static __device__ __forceinline__ unsigned short f2bf(float f) {
    union { float f; unsigned int i; } v; v.f = f;
    unsigned int x = v.i;
    return (unsigned short)((x + 0x7fffu + ((x >> 16) & 1u)) >> 16); // RNE
}
static __device__ __forceinline__ float sigmoidf(float v) {
    return 1.0f / (1.0f + expf(-v));
}

// ---------- Kernel A: grayscale patchify + 32x32 DFT magnitude + gate ----------
// grid: 1024 blocks (B*L), 256 threads
__global__ __launch_bounds__(256) void kpatch(
    const float* __restrict__ x, const float* __restrict__ lf,
    const float* __restrict__ mf, const float* __restrict__ hf,
    float* __restrict__ pr_out, unsigned short* __restrict__ mag_bf)
{
    __shared__ float sX[32][36];
    __shared__ float sYr[32][36];
    __shared__ float sYi[32][36];
    __shared__ float tc[32], ts[32];

    const int t = threadIdx.x;
    const int p = blockIdx.x;
    const int b = p >> 6, l = p & 63;
    const int gy = l >> 3, gx = l & 7;

    if (t < 32) {
        float ang = (float)t * 0.19634954084936207f; // 2*pi/32
        tc[t] = cosf(ang);
        ts[t] = sinf(ang);
    }

    // load 4 consecutive pixels per thread, grayscale
    const int y  = t >> 3;
    const int xc = (t & 7) * 4;
    const int h  = gy * 32 + y;
    const int wbase = gx * 32 + xc;
    const long long idx0 = ((long long)(b * 3 + 0) * 256 + h) * 256 + wbase;
    const long long idx1 = ((long long)(b * 3 + 1) * 256 + h) * 256 + wbase;
    const long long idx2 = ((long long)(b * 3 + 2) * 256 + h) * 256 + wbase;
    float4 r4 = *(const float4*)(x + idx0);
    float4 g4 = *(const float4*)(x + idx1);
    float4 b4 = *(const float4*)(x + idx2);
    float4 gray;
    gray.x = 0.299f * r4.x + 0.587f * g4.x + 0.114f * b4.x;
    gray.y = 0.299f * r4.y + 0.587f * g4.y + 0.114f * b4.y;
    gray.z = 0.299f * r4.z + 0.587f * g4.z + 0.114f * b4.z;
    gray.w = 0.299f * r4.w + 0.587f * g4.w + 0.114f * b4.w;
    *(float4*)&sX[y][xc] = gray;
    *(float4*)(pr_out + p * 1024 + t * 4) = gray;   // save patch for recon
    __syncthreads();

    // stage 1: Y = F * X  (rows k, columns c). F = C - iS (unnormalized)
    {
        const int k  = t >> 3;
        const int c0 = (t & 7) * 4;
        float yr[4] = {0,0,0,0}, yi[4] = {0,0,0,0};
        for (int n = 0; n < 32; n++) {
            int wi = (k * n) & 31;
            float cw = tc[wi], sw = ts[wi];
            float4 xv = *(const float4*)&sX[n][c0];
            yr[0] += cw * xv.x; yi[0] -= sw * xv.x;
            yr[1] += cw * xv.y; yi[1] -= sw * xv.y;
            yr[2] += cw * xv.z; yi[2] -= sw * xv.z;
            yr[3] += cw * xv.w; yi[3] -= sw * xv.w;
        }
        *(float4*)&sYr[k][c0] = *(float4*)yr;
        *(float4*)&sYi[k][c0] = *(float4*)yi;
    }
    __syncthreads();

    // stage 2: Z = Y * F^T, then |Z|/32 * gate
    {
        const int k  = t >> 3;
        const int m0 = (t & 7) * 4;
        float zr[4] = {0,0,0,0}, zi[4] = {0,0,0,0};
        for (int c = 0; c < 32; c++) {
            float yr = sYr[k][c];
            float yi = sYi[k][c];
            #pragma unroll
            for (int j = 0; j < 4; j++) {
                int wi = ((m0 + j) * c) & 31;
                float cw = tc[wi], sw = ts[wi];
                zr[j] += yr * cw + yi * sw;
                zi[j] += yi * cw - yr * sw;
            }
        }
        const float sl = sigmoidf(lf[0]);
        const float sm = sigmoidf(mf[0]);
        const float sh = sigmoidf(hf[0]);
        const float T1 = 480.5f / 9.0f;          // (rm/3)^2
        const float T2 = 4.0f * 480.5f / 9.0f;   // (2rm/3)^2
        const float fk = (float)k - 15.5f;
        u16x4 outv;
        #pragma unroll
        for (int j = 0; j < 4; j++) {
            float fm = (float)(m0 + j) - 15.5f;
            float r2 = fk * fk + fm * fm;
            float g = (r2 <= T1) ? sl : ((r2 <= T2) ? sm : sh);
            float magv = sqrtf(zr[j] * zr[j] + zi[j] * zi[j]) * 0.03125f * g;
            outv[j] = f2bf(magv);
        }
        *(u16x4*)(mag_bf + p * 1024 + k * 32 + m0) = outv;
    }
}

// ---------- convert + transpose W (fp32 [K][N] -> bf16 [N][K]) ----------
__global__ __launch_bounds__(256) void kconv(
    const float* __restrict__ W, unsigned short* __restrict__ WT, int K, int N)
{
    __shared__ float tile[32][33];
    const int k0 = blockIdx.x * 32, n0 = blockIdx.y * 32;
    const int tx = threadIdx.x & 31, ty = threadIdx.x >> 5; // ty in [0,8)
    #pragma unroll
    for (int i = 0; i < 4; i++) {
        int r = ty + i * 8;
        tile[r][tx] = W[(long long)(k0 + r) * N + n0 + tx];
    }
    __syncthreads();
    #pragma unroll
    for (int i = 0; i < 4; i++) {
        int r = ty + i * 8;
        WT[(long long)(n0 + r) * K + k0 + tx] = f2bf(tile[tx][r]);
    }
}

// ---------- bf16 MFMA GEMM: C(act) = act(A @ B + bias) ----------
// A: [M][K] bf16 row-major, BT: [N][K] bf16 row-major. Block = 64x64 tile (4 waves of 32x32).
// act: 0 = relu, 1 = sigmoid. Output bf16 [M][N].
__global__ __launch_bounds__(256) void kgemm(
    const unsigned short* __restrict__ A, const unsigned short* __restrict__ BT,
    const float* __restrict__ bias, unsigned short* __restrict__ C,
    int K, int N, int act)
{
    const int lane = threadIdx.x & 63;
    const int wave = threadIdx.x >> 6;
    const int wm = wave & 1, wn = wave >> 1;
    const int m_base = blockIdx.x * 64 + wm * 32;
    const int n_base = blockIdx.y * 64 + wn * 32;
    const int lr = lane & 15;
    const int koff = (lane >> 4) * 8;

    const unsigned short* pa0 = A  + (long long)(m_base + lr) * K + koff;
    const unsigned short* pa1 = pa0 + (long long)16 * K;
    const unsigned short* pb0 = BT + (long long)(n_base + lr) * K + koff;
    const unsigned short* pb1 = pb0 + (long long)16 * K;

    f32x4 acc00 = {0,0,0,0}, acc01 = {0,0,0,0}, acc10 = {0,0,0,0}, acc11 = {0,0,0,0};

    for (int kk = 0; kk < K; kk += 32) {
        bf16x8 a0 = *(const bf16x8*)(pa0 + kk);
        bf16x8 a1 = *(const bf16x8*)(pa1 + kk);
        bf16x8 b0 = *(const bf16x8*)(pb0 + kk);
        bf16x8 b1 = *(const bf16x8*)(pb1 + kk);
        acc00 = __builtin_amdgcn_mfma_f32_16x16x32_bf16(a0, b0, acc00, 0, 0, 0);
        acc01 = __builtin_amdgcn_mfma_f32_16x16x32_bf16(a0, b1, acc01, 0, 0, 0);
        acc10 = __builtin_amdgcn_mfma_f32_16x16x32_bf16(a1, b0, acc10, 0, 0, 0);
        acc11 = __builtin_amdgcn_mfma_f32_16x16x32_bf16(a1, b1, acc11, 0, 0, 0);
    }

    const int quad = lane >> 4;
    const int col0 = n_base + lr, col1 = col0 + 16;
    const float bias0 = bias[col0], bias1 = bias[col1];
    const int row0b = m_base + quad * 4;
    #pragma unroll
    for (int r = 0; r < 4; r++) {
        int row0 = row0b + r, row1 = row0 + 16;
        float v00 = acc00[r] + bias0;
        float v01 = acc01[r] + bias1;
        float v10 = acc10[r] + bias0;
        float v11 = acc11[r] + bias1;
        if (act == 0) {
            v00 = fmaxf(v00, 0.0f); v01 = fmaxf(v01, 0.0f);
            v10 = fmaxf(v10, 0.0f); v11 = fmaxf(v11, 0.0f);
        } else {
            v00 = sigmoidf(v00); v01 = sigmoidf(v01);
            v10 = sigmoidf(v10); v11 = sigmoidf(v11);
        }
        C[(long long)row0 * N + col0] = f2bf(v00);
        C[(long long)row0 * N + col1] = f2bf(v01);
        C[(long long)row1 * N + col0] = f2bf(v10);
        C[(long long)row1 * N + col1] = f2bf(v11);
    }
}

// ---------- Kernel D: per-patch modulation weight + recon fold + BN partial stats ----------
__global__ __launch_bounds__(256) void kmod(
    const unsigned short* __restrict__ mag_bf, const unsigned short* __restrict__ attn_bf,
    const float* __restrict__ pr, float* __restrict__ xrec, float* __restrict__ stats)
{
    __shared__ float red[8];
    __shared__ float sscale;
    const int t = threadIdx.x, p = blockIdx.x;
    const int lane = t & 63, wave = t >> 6;

    // dot(mag, attn)
    u16x4 mv = *(const u16x4*)(mag_bf + p * 1024 + t * 4);
    u16x4 av = *(const u16x4*)(attn_bf + p * 1024 + t * 4);
    float acc = bf2f(mv[0]) * bf2f(av[0]) + bf2f(mv[1]) * bf2f(av[1])
              + bf2f(mv[2]) * bf2f(av[2]) + bf2f(mv[3]) * bf2f(av[3]);
    #pragma unroll
    for (int off = 32; off > 0; off >>= 1) acc += __shfl_down(acc, off, 64);
    if (lane == 0) red[wave] = acc;
    __syncthreads();
    if (t == 0) {
        float s = red[0] + red[1] + red[2] + red[3];
        sscale = 1.0f + s * (1.0f / 1024.0f);
    }
    __syncthreads();
    const float sc = sscale;

    // recon + fold to x_rec
    const int b = p >> 6, l = p & 63;
    const int gy = l >> 3, gx = l & 7;
    const int y = t >> 3, xc = (t & 7) * 4;
    float4 pv = *(const float4*)(pr + p * 1024 + t * 4);
    float4 rv;
    rv.x = pv.x * sc; rv.y = pv.y * sc; rv.z = pv.z * sc; rv.w = pv.w * sc;
    *(float4*)(xrec + (long long)b * 65536 + (gy * 32 + y) * 256 + gx * 32 + xc) = rv;

    // BN partial sums
    float ls = rv.x + rv.y + rv.z + rv.w;
    float lq = rv.x * rv.x + rv.y * rv.y + rv.z * rv.z + rv.w * rv.w;
    #pragma unroll
    for (int off = 32; off > 0; off >>= 1) {
        ls += __shfl_down(ls, off, 64);
        lq += __shfl_down(lq, off, 64);
    }
    __syncthreads();
    if (lane == 0) red[wave] = ls;
    __syncthreads();
    float bs = (t == 0) ? (red[0] + red[1] + red[2] + red[3]) : 0.0f;
    __syncthreads();
    if (lane == 0) red[wave] = lq;
    __syncthreads();
    if (t == 0) {
        float bq = red[0] + red[1] + red[2] + red[3];
        atomicAdd(&stats[0], bs);
        atomicAdd(&stats[1], bq);
    }
}

// ---------- Kernel E: derive BN-collapsed per-channel affine ----------
__global__ void kstats(const float* __restrict__ stats, const float* __restrict__ w_proj,
                       const float* __restrict__ gamma, const float* __restrict__ beta,
                       float* __restrict__ der)
{
    const int c = threadIdx.x;
    const float invN = 1.0f / 1048576.0f;
    float mu  = stats[0] * invN;
    float var = stats[1] * invN - mu * mu;
    float wp = w_proj[c];
    float A = wp * gamma[c] / sqrtf(wp * wp * var + 1e-5f);
    der[c]      = A;
    der[64 + c] = beta[c];
    if (c == 0) der[128] = mu;
}

// ---------- Kernel F: broadcast to 64 channels, affine + relu ----------
__global__ __launch_bounds__(256) void kout(
    const float* __restrict__ xrec, const float* __restrict__ der, float* __restrict__ out)
{
    const int i4 = blockIdx.x * 256 + threadIdx.x;
    const int plane = i4 >> 14;       // 16384 float4 per 256x256 plane
    const int c = plane & 63;
    const int b = plane >> 6;
    const float A  = der[c];
    const float be = der[64 + c];
    const float mu = der[128];
    float4 v = ((const float4*)xrec)[b * 16384 + (i4 & 16383)];
    float4 o;
    o.x = fmaxf(fmaf(A, v.x - mu, be), 0.0f);
    o.y = fmaxf(fmaf(A, v.y - mu, be), 0.0f);
    o.z = fmaxf(fmaf(A, v.z - mu, be), 0.0f);
    o.w = fmaxf(fmaf(A, v.w - mu, be), 0.0f);
    ((float4*)out)[i4] = o;
}

// ---------- launch ----------
extern "C" void kernel_launch(void* const* d_in, const int* in_sizes, int n_in,
                              void* d_out, int out_size, void* d_ws, size_t ws_size,
                              hipStream_t stream)
{
    const float* x      = (const float*)d_in[0];
    const float* W1     = (const float*)d_in[1];
    const float* b1     = (const float*)d_in[2];
    const float* W2     = (const float*)d_in[3];
    const float* b2     = (const float*)d_in[4];
    const float* w_proj = (const float*)d_in[5];
    const float* gamma  = (const float*)d_in[6];
    const float* beta   = (const float*)d_in[7];
    const float* lf     = (const float*)d_in[8];
    const float* mf     = (const float*)d_in[9];
    const float* hf     = (const float*)d_in[10];

    char* ws = (char*)d_ws;
    float* pr                 = (float*)(ws);                    // 4 MB
    float* xrec               = (float*)(ws + 4194304);          // 4 MB
    unsigned short* mag_bf    = (unsigned short*)(ws + 8388608); // 2 MB
    unsigned short* attn_bf   = (unsigned short*)(ws + 10485760);// 2 MB
    unsigned short* hidden_bf = (unsigned short*)(ws + 12582912);// 3 MB
    unsigned short* w1t       = (unsigned short*)(ws + 15728640);// 3 MB
    unsigned short* w2t       = (unsigned short*)(ws + 18874368);// 3 MB
    float* stats              = (float*)(ws + 22020096);         // 2 floats
    float* der                = (float*)(ws + 22020224);         // 129 floats

    hipMemsetAsync(stats, 0, 8, stream);

    kconv<<<dim3(32, 48), 256, 0, stream>>>(W1, w1t, 1024, 1536);
    kconv<<<dim3(48, 32), 256, 0, stream>>>(W2, w2t, 1536, 1024);
    kpatch<<<1024, 256, 0, stream>>>(x, lf, mf, hf, pr, mag_bf);
    kgemm<<<dim3(16, 24), 256, 0, stream>>>(mag_bf, w1t, b1, hidden_bf, 1024, 1536, 0);
    kgemm<<<dim3(16, 16), 256, 0, stream>>>(hidden_bf, w2t, b2, attn_bf, 1536, 1024, 1);
    kmod<<<1024, 256, 0, stream>>>(mag_bf, attn_bf, pr, xrec, stats);
    kstats<<<1, 64, 0, stream>>>(stats, w_proj, gamma, beta, der);
    kout<<<65536, 256, 0, stream>>>(xrec, der, (float*)d_out);
}

// Round 2
// 384.962 us; speedup vs baseline: 1.0338x; 1.0338x over previous
//
#include <hip/hip_runtime.h>
#include <hip/hip_bf16.h>
#include <math.h>

// ---------- types / helpers ----------
typedef __attribute__((ext_vector_type(8))) short bf16x8;
typedef __attribute__((ext_vector_type(4))) float f32x4;
typedef __attribute__((ext_vector_type(4))) unsigned short u16x4;

static __device__ __forceinline__ float bf2f(unsigned short u) {
    union { unsigned int i; float f; } v; v.i = ((unsigned int)u) << 16; return v.f;
}
static __device__ __forceinline__ unsigned short f2bf(float f) {
    union { float f; unsigned int i; } v; v.f = f;
    unsigned int x = v.i;
    return (unsigned short)((x + 0x7fffu + ((x >> 16) & 1u)) >> 16); // RNE
}
static __device__ __forceinline__ float sigmoidf(float v) {
    return 1.0f / (1.0f + expf(-v));
}

// ---------- Kernel A: grayscale patchify + 32x32 DFT magnitude + gate + patch stats ----------
// grid: 1024 blocks (B*L), 256 threads
__global__ __launch_bounds__(256) void kpatch(
    const float* __restrict__ x, const float* __restrict__ lf,
    const float* __restrict__ mf, const float* __restrict__ hf,
    float* __restrict__ pr_out, unsigned short* __restrict__ mag_bf,
    float* __restrict__ ppsum, float* __restrict__ ppsq)
{
    __shared__ float sX[32][36];
    __shared__ float sYr[32][36];
    __shared__ float sYi[32][36];
    __shared__ float tc[32], ts[32];
    __shared__ float red_s[4], red_q[4];

    const int t = threadIdx.x;
    const int p = blockIdx.x;
    const int b = p >> 6, l = p & 63;
    const int gy = l >> 3, gx = l & 7;
    const int lane = t & 63, wave = t >> 6;

    if (t < 32) {
        float ang = (float)t * 0.19634954084936207f; // 2*pi/32
        tc[t] = cosf(ang);
        ts[t] = sinf(ang);
    }

    // load 4 consecutive pixels per thread, grayscale
    const int y  = t >> 3;
    const int xc = (t & 7) * 4;
    const int h  = gy * 32 + y;
    const int wbase = gx * 32 + xc;
    const long long idx0 = ((long long)(b * 3 + 0) * 256 + h) * 256 + wbase;
    const long long idx1 = ((long long)(b * 3 + 1) * 256 + h) * 256 + wbase;
    const long long idx2 = ((long long)(b * 3 + 2) * 256 + h) * 256 + wbase;
    float4 r4 = *(const float4*)(x + idx0);
    float4 g4 = *(const float4*)(x + idx1);
    float4 b4 = *(const float4*)(x + idx2);
    float4 gray;
    gray.x = 0.299f * r4.x + 0.587f * g4.x + 0.114f * b4.x;
    gray.y = 0.299f * r4.y + 0.587f * g4.y + 0.114f * b4.y;
    gray.z = 0.299f * r4.z + 0.587f * g4.z + 0.114f * b4.z;
    gray.w = 0.299f * r4.w + 0.587f * g4.w + 0.114f * b4.w;
    *(float4*)&sX[y][xc] = gray;
    *(float4*)(pr_out + p * 1024 + t * 4) = gray;   // save patch for recon

    // per-patch sum / sumsq (for collapsed BatchNorm stats)
    float ls = gray.x + gray.y + gray.z + gray.w;
    float lq = gray.x * gray.x + gray.y * gray.y + gray.z * gray.z + gray.w * gray.w;
    #pragma unroll
    for (int off = 32; off > 0; off >>= 1) {
        ls += __shfl_down(ls, off, 64);
        lq += __shfl_down(lq, off, 64);
    }
    if (lane == 0) { red_s[wave] = ls; red_q[wave] = lq; }
    __syncthreads();
    if (t == 0) {
        ppsum[p] = red_s[0] + red_s[1] + red_s[2] + red_s[3];
        ppsq[p]  = red_q[0] + red_q[1] + red_q[2] + red_q[3];
    }

    // stage 1: Y = F * X  (rows k, columns c). F = C - iS (unnormalized)
    {
        const int k  = t >> 3;
        const int c0 = (t & 7) * 4;
        float yr[4] = {0,0,0,0}, yi[4] = {0,0,0,0};
        for (int n = 0; n < 32; n++) {
            int wi = (k * n) & 31;
            float cw = tc[wi], sw = ts[wi];
            float4 xv = *(const float4*)&sX[n][c0];
            yr[0] += cw * xv.x; yi[0] -= sw * xv.x;
            yr[1] += cw * xv.y; yi[1] -= sw * xv.y;
            yr[2] += cw * xv.z; yi[2] -= sw * xv.z;
            yr[3] += cw * xv.w; yi[3] -= sw * xv.w;
        }
        *(float4*)&sYr[k][c0] = *(float4*)yr;
        *(float4*)&sYi[k][c0] = *(float4*)yi;
    }
    __syncthreads();

    // stage 2: Z = Y * F^T, then |Z|/32 * gate
    {
        const int k  = t >> 3;
        const int m0 = (t & 7) * 4;
        float zr[4] = {0,0,0,0}, zi[4] = {0,0,0,0};
        for (int c = 0; c < 32; c++) {
            float yr = sYr[k][c];
            float yi = sYi[k][c];
            #pragma unroll
            for (int j = 0; j < 4; j++) {
                int wi = ((m0 + j) * c) & 31;
                float cw = tc[wi], sw = ts[wi];
                zr[j] += yr * cw + yi * sw;
                zi[j] += yi * cw - yr * sw;
            }
        }
        const float sl = sigmoidf(lf[0]);
        const float sm = sigmoidf(mf[0]);
        const float sh = sigmoidf(hf[0]);
        const float T1 = 480.5f / 9.0f;          // (rm/3)^2
        const float T2 = 4.0f * 480.5f / 9.0f;   // (2rm/3)^2
        const float fk = (float)k - 15.5f;
        u16x4 outv;
        #pragma unroll
        for (int j = 0; j < 4; j++) {
            float fm = (float)(m0 + j) - 15.5f;
            float r2 = fk * fk + fm * fm;
            float g = (r2 <= T1) ? sl : ((r2 <= T2) ? sm : sh);
            float magv = sqrtf(zr[j] * zr[j] + zi[j] * zi[j]) * 0.03125f * g;
            outv[j] = f2bf(magv);
        }
        *(u16x4*)(mag_bf + p * 1024 + k * 32 + m0) = outv;
    }
}

// ---------- convert + transpose W (fp32 [K][N] -> bf16 [N][K]) ----------
__global__ __launch_bounds__(256) void kconv(
    const float* __restrict__ W, unsigned short* __restrict__ WT, int K, int N)
{
    __shared__ float tile[32][33];
    const int k0 = blockIdx.x * 32, n0 = blockIdx.y * 32;
    const int tx = threadIdx.x & 31, ty = threadIdx.x >> 5; // ty in [0,8)
    #pragma unroll
    for (int i = 0; i < 4; i++) {
        int r = ty + i * 8;
        tile[r][tx] = W[(long long)(k0 + r) * N + n0 + tx];
    }
    __syncthreads();
    #pragma unroll
    for (int i = 0; i < 4; i++) {
        int r = ty + i * 8;
        WT[(long long)(n0 + r) * K + k0 + tx] = f2bf(tile[tx][r]);
    }
}

// ---------- GEMM1: hidden = relu(mag @ W1 + b1), bf16 out, K=1024, N=1536 ----------
__global__ __launch_bounds__(256) void kgemm1(
    const unsigned short* __restrict__ A, const unsigned short* __restrict__ BT,
    const float* __restrict__ bias, unsigned short* __restrict__ C)
{
    const int K = 1024, N = 1536;
    const int lane = threadIdx.x & 63;
    const int wave = threadIdx.x >> 6;
    const int wm = wave & 1, wn = wave >> 1;
    const int m_base = blockIdx.x * 64 + wm * 32;
    const int n_base = blockIdx.y * 64 + wn * 32;
    const int lr = lane & 15;
    const int koff = (lane >> 4) * 8;

    const unsigned short* pa0 = A  + (long long)(m_base + lr) * K + koff;
    const unsigned short* pa1 = pa0 + (long long)16 * K;
    const unsigned short* pb0 = BT + (long long)(n_base + lr) * K + koff;
    const unsigned short* pb1 = pb0 + (long long)16 * K;

    f32x4 acc00 = {0,0,0,0}, acc01 = {0,0,0,0}, acc10 = {0,0,0,0}, acc11 = {0,0,0,0};

    for (int kk = 0; kk < K; kk += 32) {
        bf16x8 a0 = *(const bf16x8*)(pa0 + kk);
        bf16x8 a1 = *(const bf16x8*)(pa1 + kk);
        bf16x8 b0 = *(const bf16x8*)(pb0 + kk);
        bf16x8 b1 = *(const bf16x8*)(pb1 + kk);
        acc00 = __builtin_amdgcn_mfma_f32_16x16x32_bf16(a0, b0, acc00, 0, 0, 0);
        acc01 = __builtin_amdgcn_mfma_f32_16x16x32_bf16(a0, b1, acc01, 0, 0, 0);
        acc10 = __builtin_amdgcn_mfma_f32_16x16x32_bf16(a1, b0, acc10, 0, 0, 0);
        acc11 = __builtin_amdgcn_mfma_f32_16x16x32_bf16(a1, b1, acc11, 0, 0, 0);
    }

    const int quad = lane >> 4;
    const int col0 = n_base + lr, col1 = col0 + 16;
    const float bias0 = bias[col0], bias1 = bias[col1];
    const int row0b = m_base + quad * 4;
    #pragma unroll
    for (int r = 0; r < 4; r++) {
        int row0 = row0b + r, row1 = row0 + 16;
        C[(long long)row0 * N + col0] = f2bf(fmaxf(acc00[r] + bias0, 0.0f));
        C[(long long)row0 * N + col1] = f2bf(fmaxf(acc01[r] + bias1, 0.0f));
        C[(long long)row1 * N + col0] = f2bf(fmaxf(acc10[r] + bias0, 0.0f));
        C[(long long)row1 * N + col1] = f2bf(fmaxf(acc11[r] + bias1, 0.0f));
    }
}

// ---------- GEMM2 fused: attn = sigmoid(hidden @ W2 + b2); per-row partial dot with mag ----------
// Never materializes attn. wpart[row][cp] (cp = blockIdx.y*2 + wn, 32 partials per row).
__global__ __launch_bounds__(256) void kgemm2d(
    const unsigned short* __restrict__ A, const unsigned short* __restrict__ BT,
    const float* __restrict__ bias, const unsigned short* __restrict__ mag,
    float* __restrict__ wpart)
{
    const int K = 1536;
    const int lane = threadIdx.x & 63;
    const int wave = threadIdx.x >> 6;
    const int wm = wave & 1, wn = wave >> 1;
    const int m_base = blockIdx.x * 64 + wm * 32;
    const int n_base = blockIdx.y * 64 + wn * 32;
    const int lr = lane & 15;
    const int koff = (lane >> 4) * 8;

    const unsigned short* pa0 = A  + (long long)(m_base + lr) * K + koff;
    const unsigned short* pa1 = pa0 + (long long)16 * K;
    const unsigned short* pb0 = BT + (long long)(n_base + lr) * K + koff;
    const unsigned short* pb1 = pb0 + (long long)16 * K;

    f32x4 acc00 = {0,0,0,0}, acc01 = {0,0,0,0}, acc10 = {0,0,0,0}, acc11 = {0,0,0,0};

    for (int kk = 0; kk < K; kk += 32) {
        bf16x8 a0 = *(const bf16x8*)(pa0 + kk);
        bf16x8 a1 = *(const bf16x8*)(pa1 + kk);
        bf16x8 b0 = *(const bf16x8*)(pb0 + kk);
        bf16x8 b1 = *(const bf16x8*)(pb1 + kk);
        acc00 = __builtin_amdgcn_mfma_f32_16x16x32_bf16(a0, b0, acc00, 0, 0, 0);
        acc01 = __builtin_amdgcn_mfma_f32_16x16x32_bf16(a0, b1, acc01, 0, 0, 0);
        acc10 = __builtin_amdgcn_mfma_f32_16x16x32_bf16(a1, b0, acc10, 0, 0, 0);
        acc11 = __builtin_amdgcn_mfma_f32_16x16x32_bf16(a1, b1, acc11, 0, 0, 0);
    }

    const int quad = lane >> 4;
    const int col0 = n_base + lr, col1 = col0 + 16;
    const float bias0 = bias[col0], bias1 = bias[col1];
    const int row0b = m_base + quad * 4;

    float dsum0[4], dsum1[4];
    #pragma unroll
    for (int r = 0; r < 4; r++) {
        int row0 = row0b + r, row1 = row0 + 16;
        float v00 = sigmoidf(acc00[r] + bias0);
        float v01 = sigmoidf(acc01[r] + bias1);
        float v10 = sigmoidf(acc10[r] + bias0);
        float v11 = sigmoidf(acc11[r] + bias1);
        float m00 = bf2f(mag[(long long)row0 * 1024 + col0]);
        float m01 = bf2f(mag[(long long)row0 * 1024 + col1]);
        float m10 = bf2f(mag[(long long)row1 * 1024 + col0]);
        float m11 = bf2f(mag[(long long)row1 * 1024 + col1]);
        dsum0[r] = m00 * v00 + m01 * v01;
        dsum1[r] = m10 * v10 + m11 * v11;
    }
    // reduce across the 16 lanes of each quad (lane bits 0..3)
    #pragma unroll
    for (int r = 0; r < 4; r++) {
        #pragma unroll
        for (int mask = 8; mask > 0; mask >>= 1) {
            dsum0[r] += __shfl_xor(dsum0[r], mask, 64);
            dsum1[r] += __shfl_xor(dsum1[r], mask, 64);
        }
    }
    if (lr == 0) {
        const int cp = blockIdx.y * 2 + wn;
        #pragma unroll
        for (int r = 0; r < 4; r++) {
            wpart[(row0b + r) * 32 + cp]      = dsum0[r];
            wpart[(row0b + 16 + r) * 32 + cp] = dsum1[r];
        }
    }
}

// ---------- finalize: per-patch scale + BN-collapsed affine constants ----------
__global__ __launch_bounds__(1024) void kfin(
    const float* __restrict__ wpart, const float* __restrict__ ppsum,
    const float* __restrict__ ppsq, const float* __restrict__ w_proj,
    const float* __restrict__ gamma, const float* __restrict__ beta,
    float* __restrict__ scales, float* __restrict__ der)
{
    __shared__ float rs[16], rq[16];
    const int p = threadIdx.x;      // 0..1023 = patch id
    const int lane = p & 63, wave = p >> 6;

    const float4* wp4 = (const float4*)(wpart + p * 32);
    float w = 0.0f;
    #pragma unroll
    for (int j = 0; j < 8; j++) {
        float4 v = wp4[j];
        w += v.x + v.y + v.z + v.w;
    }
    float scale = 1.0f + w * (1.0f / 1024.0f);
    scales[p] = scale;

    float s = scale * ppsum[p];
    float q = scale * scale * ppsq[p];
    #pragma unroll
    for (int off = 32; off > 0; off >>= 1) {
        s += __shfl_down(s, off, 64);
        q += __shfl_down(q, off, 64);
    }
    if (lane == 0) { rs[wave] = s; rq[wave] = q; }
    __syncthreads();
    if (p < 64) {
        float S = (p < 16) ? rs[p] : 0.0f;
        float Q = (p < 16) ? rq[p] : 0.0f;
        #pragma unroll
        for (int off = 8; off > 0; off >>= 1) {
            S += __shfl_down(S, off, 64);
            Q += __shfl_down(Q, off, 64);
        }
        S = __shfl(S, 0, 64);
        Q = __shfl(Q, 0, 64);
        const float invN = 1.0f / 1048576.0f;
        float mu  = S * invN;
        float var = Q * invN - mu * mu;
        float wp = w_proj[p];
        float A = wp * gamma[p] / sqrtf(wp * wp * var + 1e-5f);
        der[p]      = A;
        der[64 + p] = beta[p] - A * mu;  // folded: relu(A*v + this)
    }
}

// ---------- output: broadcast to 64 channels, affine + relu (grid-stride) ----------
__global__ __launch_bounds__(256) void kout(
    const float* __restrict__ pr, const float* __restrict__ scales,
    const float* __restrict__ der, float* __restrict__ out)
{
    const int total4 = 16777216;    // 16*64*256*256 / 4
    for (int i4 = blockIdx.x * 256 + threadIdx.x; i4 < total4; i4 += gridDim.x * 256) {
        const int w4 = i4 & 63;
        const int h = (i4 >> 6) & 255;
        const int plane = i4 >> 14;
        const int c = plane & 63;
        const int b = plane >> 6;
        const int p = (b << 6) + ((h >> 5) << 3) + (w4 >> 3);
        const int off4 = ((h & 31) << 3) + (w4 & 7);
        const float As = der[c] * scales[p];
        const float D2 = der[64 + c];
        float4 v = ((const float4*)pr)[p * 256 + off4];
        float4 o;
        o.x = fmaxf(fmaf(As, v.x, D2), 0.0f);
        o.y = fmaxf(fmaf(As, v.y, D2), 0.0f);
        o.z = fmaxf(fmaf(As, v.z, D2), 0.0f);
        o.w = fmaxf(fmaf(As, v.w, D2), 0.0f);
        ((float4*)out)[i4] = o;
    }
}

// ---------- launch ----------
extern "C" void kernel_launch(void* const* d_in, const int* in_sizes, int n_in,
                              void* d_out, int out_size, void* d_ws, size_t ws_size,
                              hipStream_t stream)
{
    const float* x      = (const float*)d_in[0];
    const float* W1     = (const float*)d_in[1];
    const float* b1     = (const float*)d_in[2];
    const float* W2     = (const float*)d_in[3];
    const float* b2     = (const float*)d_in[4];
    const float* w_proj = (const float*)d_in[5];
    const float* gamma  = (const float*)d_in[6];
    const float* beta   = (const float*)d_in[7];
    const float* lf     = (const float*)d_in[8];
    const float* mf     = (const float*)d_in[9];
    const float* hf     = (const float*)d_in[10];

    char* ws = (char*)d_ws;
    float* pr                 = (float*)(ws);                      // 4 MB
    unsigned short* mag_bf    = (unsigned short*)(ws + (4u<<20));  // 2 MB
    unsigned short* hidden_bf = (unsigned short*)(ws + (6u<<20));  // 3 MB
    unsigned short* w1t       = (unsigned short*)(ws + (10u<<20)); // 3 MB
    unsigned short* w2t       = (unsigned short*)(ws + (13u<<20)); // 3 MB
    float* wpart              = (float*)(ws + (16u<<20));          // 128 KB
    float* ppsum              = (float*)(ws + (17u<<20));          // 4 KB
    float* ppsq               = (float*)(ws + (17u<<20) + 4096);   // 4 KB
    float* scales             = (float*)(ws + (17u<<20) + 8192);   // 4 KB
    float* der                = (float*)(ws + (17u<<20) + 12288);  // 512 B

    kconv<<<dim3(32, 48), 256, 0, stream>>>(W1, w1t, 1024, 1536);
    kconv<<<dim3(48, 32), 256, 0, stream>>>(W2, w2t, 1536, 1024);
    kpatch<<<1024, 256, 0, stream>>>(x, lf, mf, hf, pr, mag_bf, ppsum, ppsq);
    kgemm1<<<dim3(16, 24), 256, 0, stream>>>(mag_bf, w1t, b1, hidden_bf);
    kgemm2d<<<dim3(16, 16), 256, 0, stream>>>(hidden_bf, w2t, b2, mag_bf, wpart);
    kfin<<<1, 1024, 0, stream>>>(wpart, ppsum, ppsq, w_proj, gamma, beta, scales, der);
    kout<<<2048, 256, 0, stream>>>(pr, scales, der, (float*)d_out);
}

// Round 4
// 347.824 us; speedup vs baseline: 1.1442x; 1.1068x over previous
//
#include <hip/hip_runtime.h>
#include <hip/hip_bf16.h>
#include <math.h>

// ---------- types / helpers ----------
typedef __attribute__((ext_vector_type(8))) short bf16x8;
typedef __attribute__((ext_vector_type(4))) float f32x4;
typedef __attribute__((ext_vector_type(4))) unsigned short u16x4;

static __device__ __forceinline__ float bf2f(unsigned short u) {
    union { unsigned int i; float f; } v; v.i = ((unsigned int)u) << 16; return v.f;
}
static __device__ __forceinline__ unsigned short f2bf(float f) {
    union { float f; unsigned int i; } v; v.f = f;
    unsigned int x = v.i;
    return (unsigned short)((x + 0x7fffu + ((x >> 16) & 1u)) >> 16); // RNE
}
static __device__ __forceinline__ float sigmoidf(float v) {
    return 1.0f / (1.0f + expf(-v));
}
// async global->LDS, 16B per lane. LDS dest MUST be wave-uniform base + lane*16.
static __device__ __forceinline__ void gload16(const unsigned short* g, unsigned short* l) {
    __builtin_amdgcn_global_load_lds(
        (const __attribute__((address_space(1))) unsigned int*)g,
        (__attribute__((address_space(3))) unsigned int*)l, 16, 0, 0);
}

// ---------- Kernel A: grayscale patchify + 32x32 DFT magnitude + gate + patch stats ----------
__global__ __launch_bounds__(256) void kpatch(
    const float* __restrict__ x, const float* __restrict__ lf,
    const float* __restrict__ mf, const float* __restrict__ hf,
    float* __restrict__ pr_out, unsigned short* __restrict__ mag_bf,
    float* __restrict__ ppsum, float* __restrict__ ppsq)
{
    __shared__ float sX[32][36];
    __shared__ float sYr[32][36];
    __shared__ float sYi[32][36];
    __shared__ float tc[32], ts[32];
    __shared__ float red_s[4], red_q[4];

    const int t = threadIdx.x;
    const int p = blockIdx.x;
    const int b = p >> 6, l = p & 63;
    const int gy = l >> 3, gx = l & 7;
    const int lane = t & 63, wave = t >> 6;

    if (t < 32) {
        float ang = (float)t * 0.19634954084936207f; // 2*pi/32
        tc[t] = cosf(ang);
        ts[t] = sinf(ang);
    }

    const int y  = t >> 3;
    const int xc = (t & 7) * 4;
    const int h  = gy * 32 + y;
    const int wbase = gx * 32 + xc;
    const long long idx0 = ((long long)(b * 3 + 0) * 256 + h) * 256 + wbase;
    const long long idx1 = ((long long)(b * 3 + 1) * 256 + h) * 256 + wbase;
    const long long idx2 = ((long long)(b * 3 + 2) * 256 + h) * 256 + wbase;
    float4 r4 = *(const float4*)(x + idx0);
    float4 g4 = *(const float4*)(x + idx1);
    float4 b4 = *(const float4*)(x + idx2);
    float4 gray;
    gray.x = 0.299f * r4.x + 0.587f * g4.x + 0.114f * b4.x;
    gray.y = 0.299f * r4.y + 0.587f * g4.y + 0.114f * b4.y;
    gray.z = 0.299f * r4.z + 0.587f * g4.z + 0.114f * b4.z;
    gray.w = 0.299f * r4.w + 0.587f * g4.w + 0.114f * b4.w;
    *(float4*)&sX[y][xc] = gray;
    *(float4*)(pr_out + p * 1024 + t * 4) = gray;

    float ls = gray.x + gray.y + gray.z + gray.w;
    float lq = gray.x * gray.x + gray.y * gray.y + gray.z * gray.z + gray.w * gray.w;
    #pragma unroll
    for (int off = 32; off > 0; off >>= 1) {
        ls += __shfl_down(ls, off, 64);
        lq += __shfl_down(lq, off, 64);
    }
    if (lane == 0) { red_s[wave] = ls; red_q[wave] = lq; }
    __syncthreads();
    if (t == 0) {
        ppsum[p] = red_s[0] + red_s[1] + red_s[2] + red_s[3];
        ppsq[p]  = red_q[0] + red_q[1] + red_q[2] + red_q[3];
    }

    // stage 1: Y = F * X
    {
        const int k  = t >> 3;
        const int c0 = (t & 7) * 4;
        float yr[4] = {0,0,0,0}, yi[4] = {0,0,0,0};
        for (int n = 0; n < 32; n++) {
            int wi = (k * n) & 31;
            float cw = tc[wi], sw = ts[wi];
            float4 xv = *(const float4*)&sX[n][c0];
            yr[0] += cw * xv.x; yi[0] -= sw * xv.x;
            yr[1] += cw * xv.y; yi[1] -= sw * xv.y;
            yr[2] += cw * xv.z; yi[2] -= sw * xv.z;
            yr[3] += cw * xv.w; yi[3] -= sw * xv.w;
        }
        *(float4*)&sYr[k][c0] = *(float4*)yr;
        *(float4*)&sYi[k][c0] = *(float4*)yi;
    }
    __syncthreads();

    // stage 2: Z = Y * F^T, |Z|/32 * gate
    {
        const int k  = t >> 3;
        const int m0 = (t & 7) * 4;
        float zr[4] = {0,0,0,0}, zi[4] = {0,0,0,0};
        for (int c = 0; c < 32; c++) {
            float yr = sYr[k][c];
            float yi = sYi[k][c];
            #pragma unroll
            for (int j = 0; j < 4; j++) {
                int wi = ((m0 + j) * c) & 31;
                float cw = tc[wi], sw = ts[wi];
                zr[j] += yr * cw + yi * sw;
                zi[j] += yi * cw - yr * sw;
            }
        }
        const float sl = sigmoidf(lf[0]);
        const float sm = sigmoidf(mf[0]);
        const float sh = sigmoidf(hf[0]);
        const float T1 = 480.5f / 9.0f;
        const float T2 = 4.0f * 480.5f / 9.0f;
        const float fk = (float)k - 15.5f;
        u16x4 outv;
        #pragma unroll
        for (int j = 0; j < 4; j++) {
            float fm = (float)(m0 + j) - 15.5f;
            float r2 = fk * fk + fm * fm;
            float g = (r2 <= T1) ? sl : ((r2 <= T2) ? sm : sh);
            float magv = sqrtf(zr[j] * zr[j] + zi[j] * zi[j]) * 0.03125f * g;
            outv[j] = f2bf(magv);
        }
        *(u16x4*)(mag_bf + p * 1024 + k * 32 + m0) = outv;
    }
}

// ---------- merged convert+transpose for W1 and W2 (fp32 [K][N] -> bf16 [N][K]) ----------
__global__ __launch_bounds__(256) void kconvall(
    const float* __restrict__ W1, const float* __restrict__ W2,
    unsigned short* __restrict__ w1t, unsigned short* __restrict__ w2t)
{
    __shared__ float tile[32][33];
    int id = blockIdx.x;
    const float* W; unsigned short* WT; int K, N, k0, n0;
    if (id < 1536) {
        W = W1; WT = w1t; K = 1024; N = 1536;
        k0 = (id & 31) * 32; n0 = (id >> 5) * 32;
    } else {
        id -= 1536;
        W = W2; WT = w2t; K = 1536; N = 1024;
        k0 = (id % 48) * 32; n0 = (id / 48) * 32;
    }
    const int tx = threadIdx.x & 31, ty = threadIdx.x >> 5;
    #pragma unroll
    for (int i = 0; i < 4; i++) {
        int r = ty + i * 8;
        tile[r][tx] = W[(long long)(k0 + r) * N + n0 + tx];
    }
    __syncthreads();
    #pragma unroll
    for (int i = 0; i < 4; i++) {
        int r = ty + i * 8;
        WT[(long long)(n0 + r) * K + k0 + tx] = f2bf(tile[tx][r]);
    }
}

// ---------- GEMM1: hidden = relu(mag @ W1 + b1); LDS-staged, 64x64 tile, BK=64 ----------
__global__ __launch_bounds__(256) void kgemm1(
    const unsigned short* __restrict__ A, const unsigned short* __restrict__ BT,
    const float* __restrict__ bias, unsigned short* __restrict__ C)
{
    const int K = 1024, N = 1536;
    __shared__ unsigned short sA[64 * 64];
    __shared__ unsigned short sB[64 * 64];

    const int t = threadIdx.x;
    const int lane = t & 63, wave = t >> 6;
    const int wm = wave & 1, wn = wave >> 1;
    const int m0 = blockIdx.x * 64, n0 = blockIdx.y * 64;

    // staging: chunk u in [0,512), row r=u>>3, slot s=u&7 holds global chunk c = s^(r&7)
    const int u0 = t, u1 = t + 256;
    const int r0 = u0 >> 3, c0 = (u0 & 7) ^ (r0 & 7);
    const int r1 = u1 >> 3, c1 = (u1 & 7) ^ (r1 & 7);
    const unsigned short* agp0 = A  + (long long)(m0 + r0) * K + c0 * 8;
    const unsigned short* agp1 = A  + (long long)(m0 + r1) * K + c1 * 8;
    const unsigned short* bgp0 = BT + (long long)(n0 + r0) * K + c0 * 8;
    const unsigned short* bgp1 = BT + (long long)(n0 + r1) * K + c1 * 8;
    unsigned short* al0 = sA + u0 * 8;
    unsigned short* al1 = sA + u1 * 8;
    unsigned short* bl0 = sB + u0 * 8;
    unsigned short* bl1 = sB + u1 * 8;

    // fragment addresses
    const int lr = lane & 15, quad = lane >> 4;
    const int ra0 = wm * 32 + lr, ra1 = ra0 + 16;
    const int rb0 = wn * 32 + lr, rb1 = rb0 + 16;
    const int ea = ra0 & 7, eb = rb0 & 7;   // (r+16)&7 == r&7

    f32x4 acc00 = {0,0,0,0}, acc01 = {0,0,0,0}, acc10 = {0,0,0,0}, acc11 = {0,0,0,0};

    for (int kk = 0; kk < K; kk += 64) {
        __syncthreads();
        gload16(agp0 + kk, al0);
        gload16(agp1 + kk, al1);
        gload16(bgp0 + kk, bl0);
        gload16(bgp1 + kk, bl1);
        __syncthreads();
        #pragma unroll
        for (int st = 0; st < 2; st++) {
            const int cq = st * 4 + quad;
            bf16x8 a0 = *(const bf16x8*)(sA + ra0 * 64 + ((cq ^ ea) << 3));
            bf16x8 a1 = *(const bf16x8*)(sA + ra1 * 64 + ((cq ^ ea) << 3));
            bf16x8 b0 = *(const bf16x8*)(sB + rb0 * 64 + ((cq ^ eb) << 3));
            bf16x8 b1 = *(const bf16x8*)(sB + rb1 * 64 + ((cq ^ eb) << 3));
            acc00 = __builtin_amdgcn_mfma_f32_16x16x32_bf16(a0, b0, acc00, 0, 0, 0);
            acc01 = __builtin_amdgcn_mfma_f32_16x16x32_bf16(a0, b1, acc01, 0, 0, 0);
            acc10 = __builtin_amdgcn_mfma_f32_16x16x32_bf16(a1, b0, acc10, 0, 0, 0);
            acc11 = __builtin_amdgcn_mfma_f32_16x16x32_bf16(a1, b1, acc11, 0, 0, 0);
        }
    }

    const int col0 = n0 + wn * 32 + lr, col1 = col0 + 16;
    const float bias0 = bias[col0], bias1 = bias[col1];
    const int row0b = m0 + wm * 32 + quad * 4;
    #pragma unroll
    for (int r = 0; r < 4; r++) {
        int row0 = row0b + r, row1 = row0 + 16;
        C[(long long)row0 * N + col0] = f2bf(fmaxf(acc00[r] + bias0, 0.0f));
        C[(long long)row0 * N + col1] = f2bf(fmaxf(acc01[r] + bias1, 0.0f));
        C[(long long)row1 * N + col0] = f2bf(fmaxf(acc10[r] + bias0, 0.0f));
        C[(long long)row1 * N + col1] = f2bf(fmaxf(acc11[r] + bias1, 0.0f));
    }
}

// ---------- GEMM2 fused: attn = sigmoid(hidden @ W2 + b2); row-dot with mag -> wpart ----------
__global__ __launch_bounds__(256) void kgemm2d(
    const unsigned short* __restrict__ A, const unsigned short* __restrict__ BT,
    const float* __restrict__ bias, const unsigned short* __restrict__ mag,
    float* __restrict__ wpart)
{
    const int K = 1536;
    __shared__ unsigned short sA[64 * 64];
    __shared__ unsigned short sB[64 * 64];

    const int t = threadIdx.x;
    const int lane = t & 63, wave = t >> 6;
    const int wm = wave & 1, wn = wave >> 1;
    const int m0 = blockIdx.x * 64, n0 = blockIdx.y * 64;

    const int u0 = t, u1 = t + 256;
    const int r0 = u0 >> 3, c0 = (u0 & 7) ^ (r0 & 7);
    const int r1 = u1 >> 3, c1 = (u1 & 7) ^ (r1 & 7);
    const unsigned short* agp0 = A  + (long long)(m0 + r0) * K + c0 * 8;
    const unsigned short* agp1 = A  + (long long)(m0 + r1) * K + c1 * 8;
    const unsigned short* bgp0 = BT + (long long)(n0 + r0) * K + c0 * 8;
    const unsigned short* bgp1 = BT + (long long)(n0 + r1) * K + c1 * 8;
    unsigned short* al0 = sA + u0 * 8;
    unsigned short* al1 = sA + u1 * 8;
    unsigned short* bl0 = sB + u0 * 8;
    unsigned short* bl1 = sB + u1 * 8;

    const int lr = lane & 15, quad = lane >> 4;
    const int ra0 = wm * 32 + lr, ra1 = ra0 + 16;
    const int rb0 = wn * 32 + lr, rb1 = rb0 + 16;
    const int ea = ra0 & 7, eb = rb0 & 7;

    f32x4 acc00 = {0,0,0,0}, acc01 = {0,0,0,0}, acc10 = {0,0,0,0}, acc11 = {0,0,0,0};

    for (int kk = 0; kk < K; kk += 64) {
        __syncthreads();
        gload16(agp0 + kk, al0);
        gload16(agp1 + kk, al1);
        gload16(bgp0 + kk, bl0);
        gload16(bgp1 + kk, bl1);
        __syncthreads();
        #pragma unroll
        for (int st = 0; st < 2; st++) {
            const int cq = st * 4 + quad;
            bf16x8 a0 = *(const bf16x8*)(sA + ra0 * 64 + ((cq ^ ea) << 3));
            bf16x8 a1 = *(const bf16x8*)(sA + ra1 * 64 + ((cq ^ ea) << 3));
            bf16x8 b0 = *(const bf16x8*)(sB + rb0 * 64 + ((cq ^ eb) << 3));
            bf16x8 b1 = *(const bf16x8*)(sB + rb1 * 64 + ((cq ^ eb) << 3));
            acc00 = __builtin_amdgcn_mfma_f32_16x16x32_bf16(a0, b0, acc00, 0, 0, 0);
            acc01 = __builtin_amdgcn_mfma_f32_16x16x32_bf16(a0, b1, acc01, 0, 0, 0);
            acc10 = __builtin_amdgcn_mfma_f32_16x16x32_bf16(a1, b0, acc10, 0, 0, 0);
            acc11 = __builtin_amdgcn_mfma_f32_16x16x32_bf16(a1, b1, acc11, 0, 0, 0);
        }
    }

    const int col0 = n0 + wn * 32 + lr, col1 = col0 + 16;
    const float bias0 = bias[col0], bias1 = bias[col1];
    const int row0b = m0 + wm * 32 + quad * 4;

    float dsum0[4], dsum1[4];
    #pragma unroll
    for (int r = 0; r < 4; r++) {
        int row0 = row0b + r, row1 = row0 + 16;
        float v00 = sigmoidf(acc00[r] + bias0);
        float v01 = sigmoidf(acc01[r] + bias1);
        float v10 = sigmoidf(acc10[r] + bias0);
        float v11 = sigmoidf(acc11[r] + bias1);
        float m00 = bf2f(mag[(long long)row0 * 1024 + col0]);
        float m01 = bf2f(mag[(long long)row0 * 1024 + col1]);
        float m10 = bf2f(mag[(long long)row1 * 1024 + col0]);
        float m11 = bf2f(mag[(long long)row1 * 1024 + col1]);
        dsum0[r] = m00 * v00 + m01 * v01;
        dsum1[r] = m10 * v10 + m11 * v11;
    }
    #pragma unroll
    for (int r = 0; r < 4; r++) {
        #pragma unroll
        for (int mask = 8; mask > 0; mask >>= 1) {
            dsum0[r] += __shfl_xor(dsum0[r], mask, 64);
            dsum1[r] += __shfl_xor(dsum1[r], mask, 64);
        }
    }
    if (lr == 0) {
        const int cp = blockIdx.y * 2 + wn;
        #pragma unroll
        for (int r = 0; r < 4; r++) {
            wpart[(row0b + r) * 32 + cp]      = dsum0[r];
            wpart[(row0b + 16 + r) * 32 + cp] = dsum1[r];
        }
    }
}

// ---------- finalize: per-patch scale + BN-collapsed affine constants ----------
__global__ __launch_bounds__(1024) void kfin(
    const float* __restrict__ wpart, const float* __restrict__ ppsum,
    const float* __restrict__ ppsq, const float* __restrict__ w_proj,
    const float* __restrict__ gamma, const float* __restrict__ beta,
    float* __restrict__ scales, float* __restrict__ der)
{
    __shared__ float rs[16], rq[16];
    const int p = threadIdx.x;
    const int lane = p & 63, wave = p >> 6;

    const float4* wp4 = (const float4*)(wpart + p * 32);
    float w = 0.0f;
    #pragma unroll
    for (int j = 0; j < 8; j++) {
        float4 v = wp4[j];
        w += v.x + v.y + v.z + v.w;
    }
    float scale = 1.0f + w * (1.0f / 1024.0f);
    scales[p] = scale;

    float s = scale * ppsum[p];
    float q = scale * scale * ppsq[p];
    #pragma unroll
    for (int off = 32; off > 0; off >>= 1) {
        s += __shfl_down(s, off, 64);
        q += __shfl_down(q, off, 64);
    }
    if (lane == 0) { rs[wave] = s; rq[wave] = q; }
    __syncthreads();
    if (p < 64) {
        float S = (p < 16) ? rs[p] : 0.0f;
        float Q = (p < 16) ? rq[p] : 0.0f;
        #pragma unroll
        for (int off = 8; off > 0; off >>= 1) {
            S += __shfl_down(S, off, 64);
            Q += __shfl_down(Q, off, 64);
        }
        S = __shfl(S, 0, 64);
        Q = __shfl(Q, 0, 64);
        const float invN = 1.0f / 1048576.0f;
        float mu  = S * invN;
        float var = Q * invN - mu * mu;
        float wp = w_proj[p];
        float A = wp * gamma[p] / sqrtf(wp * wp * var + 1e-5f);
        der[p]      = A;
        der[64 + p] = beta[p] - A * mu;
    }
}

// ---------- output: broadcast to 64 channels, affine + relu (grid-stride, NT stores) ----------
__global__ __launch_bounds__(256) void kout(
    const float* __restrict__ pr, const float* __restrict__ scales,
    const float* __restrict__ der, float* __restrict__ out)
{
    const int total4 = 16777216;
    for (int i4 = blockIdx.x * 256 + threadIdx.x; i4 < total4; i4 += gridDim.x * 256) {
        const int w4 = i4 & 63;
        const int h = (i4 >> 6) & 255;
        const int plane = i4 >> 14;
        const int c = plane & 63;
        const int b = plane >> 6;
        const int p = (b << 6) + ((h >> 5) << 3) + (w4 >> 3);
        const int off4 = ((h & 31) << 3) + (w4 & 7);
        const float As = der[c] * scales[p];
        const float D2 = der[64 + c];
        float4 v = ((const float4*)pr)[p * 256 + off4];
        f32x4 o;
        o[0] = fmaxf(fmaf(As, v.x, D2), 0.0f);
        o[1] = fmaxf(fmaf(As, v.y, D2), 0.0f);
        o[2] = fmaxf(fmaf(As, v.z, D2), 0.0f);
        o[3] = fmaxf(fmaf(As, v.w, D2), 0.0f);
        __builtin_nontemporal_store(o, (f32x4*)out + i4);
    }
}

// ---------- launch ----------
extern "C" void kernel_launch(void* const* d_in, const int* in_sizes, int n_in,
                              void* d_out, int out_size, void* d_ws, size_t ws_size,
                              hipStream_t stream)
{
    const float* x      = (const float*)d_in[0];
    const float* W1     = (const float*)d_in[1];
    const float* b1     = (const float*)d_in[2];
    const float* W2     = (const float*)d_in[3];
    const float* b2     = (const float*)d_in[4];
    const float* w_proj = (const float*)d_in[5];
    const float* gamma  = (const float*)d_in[6];
    const float* beta   = (const float*)d_in[7];
    const float* lf     = (const float*)d_in[8];
    const float* mf     = (const float*)d_in[9];
    const float* hf     = (const float*)d_in[10];

    char* ws = (char*)d_ws;
    float* pr                 = (float*)(ws);                      // 4 MB
    unsigned short* mag_bf    = (unsigned short*)(ws + (4u<<20));  // 2 MB
    unsigned short* hidden_bf = (unsigned short*)(ws + (6u<<20));  // 3 MB
    unsigned short* w1t       = (unsigned short*)(ws + (10u<<20)); // 3 MB
    unsigned short* w2t       = (unsigned short*)(ws + (13u<<20)); // 3 MB
    float* wpart              = (float*)(ws + (16u<<20));          // 128 KB
    float* ppsum              = (float*)(ws + (17u<<20));          // 4 KB
    float* ppsq               = (float*)(ws + (17u<<20) + 4096);   // 4 KB
    float* scales             = (float*)(ws + (17u<<20) + 8192);   // 4 KB
    float* der                = (float*)(ws + (17u<<20) + 12288);  // 512 B

    kconvall<<<3072, 256, 0, stream>>>(W1, W2, w1t, w2t);
    kpatch<<<1024, 256, 0, stream>>>(x, lf, mf, hf, pr, mag_bf, ppsum, ppsq);
    kgemm1<<<dim3(16, 24), 256, 0, stream>>>(mag_bf, w1t, b1, hidden_bf);
    kgemm2d<<<dim3(16, 16), 256, 0, stream>>>(hidden_bf, w2t, b2, mag_bf, wpart);
    kfin<<<1, 1024, 0, stream>>>(wpart, ppsum, ppsq, w_proj, gamma, beta, scales, der);
    kout<<<2048, 256, 0, stream>>>(pr, scales, der, (float*)d_out);
}